// Round 2
// baseline (668.527 us; speedup 1.0000x reference)
//
#include <hip/hip_runtime.h>

typedef unsigned short u16;
typedef unsigned int   u32;
typedef __bf16 bf16x8 __attribute__((ext_vector_type(8)));
typedef float  f32x4  __attribute__((ext_vector_type(4)));

// ---------- helpers ----------
__device__ __forceinline__ float bf2f(u16 v){ u32 u = ((u32)v) << 16; float f; __builtin_memcpy(&f,&u,4); return f; }
__device__ __forceinline__ u16 f2bf(float f){ u32 u; __builtin_memcpy(&u,&f,4); u32 r = (u + 0x7FFFu + ((u>>16)&1u)) >> 16; return (u16)r; }
__device__ __forceinline__ float silu(float v){ return v / (1.f + __expf(-v)); }

__device__ __forceinline__ void gload_lds16(const u16* g, u16* l){
  __builtin_amdgcn_global_load_lds((const __attribute__((address_space(1))) void*)g,
                                   (__attribute__((address_space(3))) void*)l, 16, 0, 0);
}

#define FENCE asm volatile("" ::: "memory")
#define BARRIER do{ FENCE; __builtin_amdgcn_s_barrier(); FENCE; }while(0)

// Geometry: B=16, C1=128, C2=256, H=W=128, padded spatial 130x130 (1-px zero halo)
#define HP 130
#define XPIX 128              // channels per pixel in x_pad (bf16)
#define YPIX 256              // channels per pixel in y_pad (bf16)
#define XIMG (HP*HP*XPIX)
#define YIMG (HP*HP*YPIX)

// ---------- small prep kernels (fp32 -> bf16 boundary lives here) ----------
__global__ void prep_coef(const float* __restrict__ gamma, const float* __restrict__ beta,
                          const float* __restrict__ mean,  const float* __restrict__ var,
                          const float* __restrict__ b1, float2* __restrict__ coefA, float2* __restrict__ coefB){
  int c = threadIdx.x;
  float s = gamma[c] * rsqrtf(var[c] + 1e-5f);
  float t = beta[c] - mean[c] * s;
  coefA[c] = make_float2(s, t);
  coefB[c] = make_float2(s, b1[c] * s + t);   // fold 1x1 bias into BN shift
}

// w3p[n][k] bf16, k = (kh*3+kw)*128 + c   (matches act K-order (kh,kw,c))
__global__ void repack_w3(const float* __restrict__ w, u16* __restrict__ w3p){
  int idx = blockIdx.x*256 + threadIdx.x;        // n*1152 + k
  int n = idx / 1152, k = idx % 1152;
  int tap = k >> 7, c = k & 127;
  int kh = tap / 3, kw = tap % 3;
  w3p[idx] = f2bf(w[((n*128 + c)*3 + kh)*3 + kw]);
}

// w1p[n][k] bf16 (1x1 conv weight is already [n][c][1][1])
__global__ void repack_w1(const float* __restrict__ w, u16* __restrict__ w1p){
  int idx = blockIdx.x*256 + threadIdx.x;        // 65536 total
  w1p[idx] = f2bf(w[idx]);
}

// zero only the halo rings of x_pad and y_pad chunk buffers
__device__ __forceinline__ void halo_pix(int pi, int& hp, int& wp){
  if (pi < 130){ hp = 0; wp = pi; }
  else if (pi < 260){ hp = 129; wp = pi - 130; }
  else { int j = pi - 260; hp = 1 + (j >> 1); wp = (j & 1) ? 129 : 0; }
}
__global__ void zero_halos(u16* __restrict__ xpad, u16* __restrict__ ypad, int cimg){
  int idx = blockIdx.x*256 + threadIdx.x;
  const int NX = cimg*516*16;
  uint4 z = make_uint4(0u,0u,0u,0u);
  if (idx < NX){
    int b = idx / (516*16), rr = idx % (516*16);
    int pi = rr >> 4, cch = rr & 15, hp, wp;
    halo_pix(pi, hp, wp);
    *(uint4*)(xpad + (((size_t)b*HP + hp)*HP + wp)*XPIX + cch*8) = z;
  } else {
    idx -= NX;
    if (idx < cimg*516*32){
      int b = idx / (516*32), rr = idx % (516*32);
      int pi = rr >> 5, cch = rr & 31, hp, wp;
      halo_pix(pi, hp, wp);
      *(uint4*)(ypad + (((size_t)b*HP + hp)*HP + wp)*YPIX + cch*8) = z;
    }
  }
}

// fp32 NCHW -> padded bf16 NHWC transpose, 64x64 (c x w) tiles via LDS
__global__ __launch_bounds__(256) void transpose_x(const float* __restrict__ x, u16* __restrict__ xpad, int b0){
  __shared__ u16 s[64][66];
  const int tid = threadIdx.x, bid = blockIdx.x;
  const int ct = bid & 1, wt = (bid >> 1) & 1, row = bid >> 2;
  const int bl = row >> 7, h = row & 127;
  const int c0 = ct << 6, w0 = wt << 6;
  {
    const int lw = tid & 63, lc4 = tid >> 6;     // one wave spans one c-row (coalesced fp32)
    const size_t xb = ((size_t)(b0 + bl)*128)*16384 + (size_t)h*128 + w0 + lw;
    #pragma unroll
    for (int r = 0; r < 16; ++r){
      int c = r*4 + lc4;
      s[c][lw] = f2bf(x[xb + (size_t)(c0 + c)*16384]);
    }
  }
  __syncthreads();
  {
    const int lw = tid >> 5, lcp = (tid & 31) << 1;
    const size_t pb = ((size_t)bl*HP + h + 1)*HP;
    #pragma unroll
    for (int r = 0; r < 8; ++r){
      int w = r*8 + lw;
      u32 v = (u32)s[lcp][w] | ((u32)s[lcp+1][w] << 16);
      *(u32*)(xpad + (pb + (w0 + w + 1))*XPIX + c0 + lcp) = v;
    }
  }
}

// ---------- stage A: conv3x3 implicit GEMM, 256x256 tile, BK=64, 8-phase schedule ----------
// Staging addresses split into per-thread base (prologue) + wave-uniform per-tile offset
// (SALU) so main-loop VALU is ~1 add per load instead of div/mul chains.

struct StgDesc { const u16* g[2][2]; int l[2][2]; };   // [variant][q]: global base, LDS elem offset

// uniform conv-tap offset for A staging at K-tile Ts (elements)
__device__ __forceinline__ int offA_of(int Ts){
  int tap = Ts >> 1;
  int kh = (tap*11) >> 5;            // tap/3 for tap<=9
  int kw = tap - kh*3;
  return kh*(HP*XPIX) + kw*XPIX + ((Ts & 1) << 6);
}

template<int V>
__device__ __forceinline__ void stage2(u16* lds, const StgDesc& d, int offE){
  gload_lds16(d.g[V][0] + offE, lds + d.l[V][0]);
  gload_lds16(d.g[V][1] + offE, lds + d.l[V][1]);
}

__global__ __launch_bounds__(512, 2) void convA(const u16* __restrict__ xpad, const u16* __restrict__ w3p,
                                                const float2* __restrict__ coefA, u16* __restrict__ ypad){
  __shared__ u16 sA[2][256*64];
  __shared__ u16 sB[2][256*64];
  const int t = threadIdx.x;
  const int nwg = gridDim.x;
  const int bid = blockIdx.x;
  const int bsz = (bid & 7)*(nwg >> 3) + (bid >> 3);   // XCD-contiguous row bands (nwg%8==0)
  const int bl = bsz >> 6;
  const int h0 = (bsz & 63) << 1;                      // row pair
  const int lane = t & 63, wave = t >> 6;
  const int wm = wave & 1, wn = wave >> 1;             // 2 (M) x 4 (N) waves
  const int quad = lane >> 4, l16 = lane & 15;
  const int lc = t & 7;
  const u16* ximg = xpad + (size_t)bl * XIMG;

  // --- per-thread staging descriptors (computed once) ---
  StgDesc da, db;      // da: [ho][q] activation, db: [bo][q] weights
  #pragma unroll
  for (int ho = 0; ho < 2; ++ho)
    #pragma unroll
    for (int q = 0; q < 2; ++q){
      int r = ((t >> 6) << 4) + (q << 3) + ((t >> 3) & 7);
      int p = (ho << 6) + r + (r & 64);                // even/odd 64-row quarters
      da.g[ho][q] = ximg + (size_t)((h0 + (p >> 7))*HP + (p & 127))*XPIX + ((lc ^ (p & 7)) << 3);
      da.l[ho][q] = p*64 + lc*8;
    }
  #pragma unroll
  for (int bo = 0; bo < 2; ++bo)
    #pragma unroll
    for (int q = 0; q < 2; ++q){
      int r = ((t >> 6) << 4) + (q << 3) + ((t >> 3) & 7);
      int n = ((r >> 5) << 6) + (bo << 5) + (r & 31);  // n-half quarters
      db.g[bo][q] = w3p + (size_t)n*1152 + ((lc ^ (n & 7)) << 3);
      db.l[bo][q] = n*64 + lc*8;
    }

  // --- per-thread LDS fragment byte... element offsets (computed once) ---
  u32 fA[4][2][2], fB[2][2][2];
  #pragma unroll
  for (int i = 0; i < 4; ++i)
    #pragma unroll
    for (int hf = 0; hf < 2; ++hf)
      #pragma unroll
      for (int c = 0; c < 2; ++c){
        int row = wm*128 + hf*64 + i*16 + l16;
        fA[i][hf][c] = row*64 + (((c*4 + quad) ^ (row & 7)) << 3);
      }
  #pragma unroll
  for (int j = 0; j < 2; ++j)
    #pragma unroll
    for (int hf = 0; hf < 2; ++hf)
      #pragma unroll
      for (int c = 0; c < 2; ++c){
        int row = wn*64 + hf*32 + j*16 + l16;
        fB[j][hf][c] = row*64 + (((c*4 + quad) ^ (row & 7)) << 3);
      }

  f32x4 acc[8][4];
  #pragma unroll
  for (int i = 0; i < 8; ++i)
    #pragma unroll
    for (int j = 0; j < 4; ++j){ f32x4 z = {0.f,0.f,0.f,0.f}; acc[i][j] = z; }

  // prologue: T0 fully (h0,h1,h2,h3), then T1 h0,h1,h2  (last 6 loads = T1's halves)
  {
    const int o0 = offA_of(0), o1 = offA_of(1);
    stage2<0>(sA[0], da, o0);          // T0.h0
    stage2<0>(sB[0], db, 0);           // T0.h1
    stage2<1>(sB[0], db, 0);           // T0.h2
    stage2<1>(sA[0], da, o0);          // T0.h3
    stage2<0>(sA[1], da, o1);          // T1.h0
    stage2<0>(sB[1], db, 64);          // T1.h1
    stage2<1>(sB[1], db, 64);          // T1.h2
    asm volatile("s_waitcnt vmcnt(6)" ::: "memory");
  }
  BARRIER;

  for (int T = 0; T < 18; ++T){
    const int pr = T & 1;
    const u16* A = sA[pr];
    const u16* B = sB[pr];
    u16* An = sA[pr ^ 1];
    bf16x8 a[4][2], b0[2][2], b1[2][2];

    // ---- q0: read A(mh0) + B(nh0); stage (T+1).h3 ----
    #pragma unroll
    for (int i = 0; i < 4; ++i){
      a[i][0] = *(const bf16x8*)(A + fA[i][0][0]);
      a[i][1] = *(const bf16x8*)(A + fA[i][0][1]);
    }
    #pragma unroll
    for (int j = 0; j < 2; ++j){
      b0[j][0] = *(const bf16x8*)(B + fB[j][0][0]);
      b0[j][1] = *(const bf16x8*)(B + fB[j][0][1]);
    }
    if (T + 1 < 18) stage2<1>(An, da, offA_of(T+1));
    BARRIER;
    __builtin_amdgcn_s_setprio(1);
    #pragma unroll
    for (int i = 0; i < 4; ++i)
      #pragma unroll
      for (int j = 0; j < 2; ++j){
        acc[i][j] = __builtin_amdgcn_mfma_f32_16x16x32_bf16(a[i][0], b0[j][0], acc[i][j], 0, 0, 0);
        acc[i][j] = __builtin_amdgcn_mfma_f32_16x16x32_bf16(a[i][1], b0[j][1], acc[i][j], 0, 0, 0);
      }
    __builtin_amdgcn_s_setprio(0);
    BARRIER;

    // ---- q1: read B(nh1); stage (T+2).h0 ----
    #pragma unroll
    for (int j = 0; j < 2; ++j){
      b1[j][0] = *(const bf16x8*)(B + fB[j][1][0]);
      b1[j][1] = *(const bf16x8*)(B + fB[j][1][1]);
    }
    if (T + 2 < 18) stage2<0>((u16*)A, da, offA_of(T+2));   // (T+2)&1 == pr
    BARRIER;
    __builtin_amdgcn_s_setprio(1);
    #pragma unroll
    for (int i = 0; i < 4; ++i)
      #pragma unroll
      for (int j = 0; j < 2; ++j){
        acc[i][2+j] = __builtin_amdgcn_mfma_f32_16x16x32_bf16(a[i][0], b1[j][0], acc[i][2+j], 0, 0, 0);
        acc[i][2+j] = __builtin_amdgcn_mfma_f32_16x16x32_bf16(a[i][1], b1[j][1], acc[i][2+j], 0, 0, 0);
      }
    __builtin_amdgcn_s_setprio(0);
    BARRIER;

    // ---- q2: read A(mh1); stage (T+2).h1 ----
    #pragma unroll
    for (int i = 0; i < 4; ++i){
      a[i][0] = *(const bf16x8*)(A + fA[i][1][0]);
      a[i][1] = *(const bf16x8*)(A + fA[i][1][1]);
    }
    if (T + 2 < 18) stage2<0>((u16*)(B), db, (T+2)*64);
    BARRIER;
    __builtin_amdgcn_s_setprio(1);
    #pragma unroll
    for (int i = 0; i < 4; ++i)
      #pragma unroll
      for (int j = 0; j < 2; ++j){
        acc[4+i][2+j] = __builtin_amdgcn_mfma_f32_16x16x32_bf16(a[i][0], b1[j][0], acc[4+i][2+j], 0, 0, 0);
        acc[4+i][2+j] = __builtin_amdgcn_mfma_f32_16x16x32_bf16(a[i][1], b1[j][1], acc[4+i][2+j], 0, 0, 0);
      }
    __builtin_amdgcn_s_setprio(0);
    BARRIER;

    // ---- q3: no reads (b0 kept in regs); stage (T+2).h2 ----
    if (T + 2 < 18) stage2<1>((u16*)(B), db, (T+2)*64);
    BARRIER;
    __builtin_amdgcn_s_setprio(1);
    #pragma unroll
    for (int i = 0; i < 4; ++i)
      #pragma unroll
      for (int j = 0; j < 2; ++j){
        acc[4+i][j] = __builtin_amdgcn_mfma_f32_16x16x32_bf16(a[i][0], b0[j][0], acc[4+i][j], 0, 0, 0);
        acc[4+i][j] = __builtin_amdgcn_mfma_f32_16x16x32_bf16(a[i][1], b0[j][1], acc[4+i][j], 0, 0, 0);
      }
    __builtin_amdgcn_s_setprio(0);
    if (T < 16)       asm volatile("s_waitcnt vmcnt(6)" ::: "memory");
    else if (T == 16) asm volatile("s_waitcnt vmcnt(0)" ::: "memory");
    BARRIER;
  }

  // epilogue: BN + SiLU -> ypad (NHWC bf16)
  // D[p = wm*128 + ig*16 + quad*4 + r][ch = wn*64 + jg*16 + l16]
  float2 co[4];
  #pragma unroll
  for (int j = 0; j < 4; ++j) co[j] = coefA[wn*64 + j*16 + l16];
  #pragma unroll
  for (int ig = 0; ig < 8; ++ig){
    const int pb = wm*128 + ig*16 + quad*4;
    #pragma unroll
    for (int r = 0; r < 4; ++r){
      const int p = pb + r;
      const int hh = h0 + (p >> 7), ww = p & 127;
      u16* dst = ypad + ((size_t)(bl*HP + hh + 1)*HP + (ww + 1))*YPIX + wn*64;
      #pragma unroll
      for (int j = 0; j < 4; ++j){
        float v = acc[ig][j][r]*co[j].x + co[j].y;
        dst[j*16 + l16] = f2bf(silu(v));
      }
    }
  }
}

// ---------- stage B: shift + conv1x1 + bias + BN + residual + SiLU -> out (NCHW fp32) ----------
// Double-buffered LDS, 2-phase pipeline: issue kt+1 stage before kt's reads+MFMA.
__device__ __forceinline__ void stgB(u16* act, u16* w, const u16* __restrict__ ypad,
                                     size_t imgy, int h, int kt, int r0, int sub, int tid,
                                     const u16* w_row0, const u16* w_row1){
  const int g = kt >> 1;
  const int dhp = (g == 0 || g == 2) ? 1 : (g == 1 ? 2 : 0);
  const int dwp = (g == 1 || g == 3) ? 1 : (g == 0 ? 0 : 2);
  const size_t rb = imgy + (size_t)((h + dhp)*HP)*YPIX + kt*32 + sub*8;
  gload_lds16(ypad + rb + (size_t)(r0 + dwp)*YPIX,      act + tid*8);
  gload_lds16(ypad + rb + (size_t)(r0 + 64 + dwp)*YPIX, act + 2048 + tid*8);
  gload_lds16(w_row0 + kt*32, w + tid*8);
  gload_lds16(w_row1 + kt*32, w + 2048 + tid*8);
}

__global__ __launch_bounds__(256) void convB(const u16* __restrict__ ypad, const u16* __restrict__ w1p,
                                             const float2* __restrict__ coefB, float* __restrict__ out, int b0){
  __shared__ u16 sAct[2][4096];  // act [p=128][k=32], double-buffered
  __shared__ u16 sW[2][4096];    // wts [n=128][k=32], double-buffered
  const int tid = threadIdx.x;
  const int nwg = gridDim.x;
  const int bidl = (blockIdx.x & 7)*(nwg >> 3) + (blockIdx.x >> 3);  // XCD swizzle (nwg%8==0)
  const int nt = bidl & 1, row = bidl >> 1;
  const int bl = row >> 7, h = row & 127;
  const int n0 = nt << 7;
  const int lane = tid & 63, wave = tid >> 6;
  const int wc = wave & 1, wpx = wave >> 1;
  const int quad = lane >> 4, l16 = lane & 15;
  const int r0 = tid >> 2, sub = tid & 3;

  f32x4 acc[4][4];
  #pragma unroll
  for (int i = 0; i < 4; ++i)
    #pragma unroll
    for (int j = 0; j < 4; ++j){ f32x4 zz = {0.f,0.f,0.f,0.f}; acc[i][j] = zz; }

  const size_t imgy = (size_t)bl * YIMG;
  const u16* w_row0 = w1p + (size_t)(n0 + r0)*256 + sub*8;
  const u16* w_row1 = w_row0 + (size_t)64*256;

  stgB(sAct[0], sW[0], ypad, imgy, h, 0, r0, sub, tid, w_row0, w_row1);
  asm volatile("s_waitcnt vmcnt(0)" ::: "memory");
  BARRIER;

  // shift taps in padded coords: g0:y[h][w-1] g1:y[h+1][w] g2:y[h][w+1] g3:y[h-1][w]
  #pragma unroll
  for (int kt = 0; kt < 8; ++kt){
    const int cur = kt & 1;
    if (kt < 7) stgB(sAct[cur^1], sW[cur^1], ypad, imgy, h, kt+1, r0, sub, tid, w_row0, w_row1);

    bf16x8 wf[4], af[4];
    #pragma unroll
    for (int i = 0; i < 4; ++i) wf[i] = *(const bf16x8*)&sW[cur][(wc*64 + i*16 + l16)*32 + quad*8];
    #pragma unroll
    for (int j = 0; j < 4; ++j) af[j] = *(const bf16x8*)&sAct[cur][(wpx*64 + j*16 + l16)*32 + quad*8];
    __builtin_amdgcn_s_setprio(1);
    #pragma unroll
    for (int i = 0; i < 4; ++i)
      #pragma unroll
      for (int j = 0; j < 4; ++j)
        acc[i][j] = __builtin_amdgcn_mfma_f32_16x16x32_bf16(wf[i], af[j], acc[i][j], 0, 0, 0);
    __builtin_amdgcn_s_setprio(0);
    asm volatile("s_waitcnt vmcnt(0)" ::: "memory");
    BARRIER;
  }

  // D[channel = n0+wc*64+i*16+quad*4+r][pixel = wpx*64+j*16+l16]
  const size_t ybase = ((size_t)(bl*HP + h + 1))*HP*YPIX;
  const size_t obase = (size_t)(b0 + bl)*256*16384 + (size_t)h*128;
  #pragma unroll
  for (int i = 0; i < 4; ++i){
    const int chb = n0 + wc*64 + i*16 + quad*4;
    const float2 c0 = coefB[chb+0], c1 = coefB[chb+1], c2 = coefB[chb+2], c3 = coefB[chb+3];
    float* ob = out + obase + (size_t)chb*16384;
    #pragma unroll
    for (int j = 0; j < 4; ++j){
      const int p = wpx*64 + j*16 + l16;
      const ushort4 rv = *(const ushort4*)&ypad[ybase + (size_t)(p + 1)*YPIX + chb];  // residual, 4 ch
      ob[p]             = silu(acc[i][j][0]*c0.x + c0.y + bf2f(rv.x));
      ob[16384 + p]     = silu(acc[i][j][1]*c1.x + c1.y + bf2f(rv.y));
      ob[2*16384 + p]   = silu(acc[i][j][2]*c2.x + c2.y + bf2f(rv.z));
      ob[3*16384 + p]   = silu(acc[i][j][3]*c3.x + c3.y + bf2f(rv.w));
    }
  }
}

// ---------- launch ----------
extern "C" void kernel_launch(void* const* d_in, const int* in_sizes, int n_in,
                              void* d_out, int out_size, void* d_ws, size_t ws_size,
                              hipStream_t stream){
  const float* x  = (const float*)d_in[0];
  const float* w3 = (const float*)d_in[1];
  const float* w1 = (const float*)d_in[2];
  const float* b1 = (const float*)d_in[3];
  const float* gm = (const float*)d_in[4];
  const float* bt = (const float*)d_in[5];
  const float* mn = (const float*)d_in[6];
  const float* vr = (const float*)d_in[7];
  float* outp = (float*)d_out;

  // workspace: small buffers first, then chunk-sized padded image buffers
  char* ws = (char*)d_ws;
  float2* coefA = (float2*)ws;                                // 2048 B
  float2* coefB = coefA + 256;                                // 2048 B
  u16*    w3p   = (u16*)(ws + 4096);                          // 589,824 B
  u16*    w1p   = (u16*)(ws + 4096 + 589824);                 // 131,072 B
  const size_t fixed = 4096 + 589824 + 131072;                // 724,992 B (16B aligned)
  // per-image: xpad 4,326,400 B + ypad 8,652,800 B = 12,979,200 B
  int cimg = 16;
  while (cimg > 1 && fixed + (size_t)cimg*12979200ull > ws_size) cimg >>= 1;
  u16* xpad = (u16*)(ws + fixed);
  u16* ypad = (u16*)(ws + fixed + (size_t)cimg*4326400ull);

  prep_coef<<<1, 256, 0, stream>>>(gm, bt, mn, vr, b1, coefA, coefB);
  repack_w3<<<1152, 256, 0, stream>>>(w3, w3p);
  repack_w1<<<256, 256, 0, stream>>>(w1, w1p);
  {
    int nthr = cimg*516*48;
    zero_halos<<<(nthr + 255)/256, 256, 0, stream>>>(xpad, ypad, cimg);
  }
  for (int b0 = 0; b0 < 16; b0 += cimg){
    transpose_x<<<4*128*cimg, 256, 0, stream>>>(x, xpad, b0);
    convA<<<64*cimg, 512, 0, stream>>>(xpad, w3p, coefA, ypad);
    convB<<<2*128*cimg, 256, 0, stream>>>(ypad, w1p, coefB, outp, b0);
  }
}

// Round 3
// 651.029 us; speedup vs baseline: 1.0269x; 1.0269x over previous
//
#include <hip/hip_runtime.h>

typedef unsigned short u16;
typedef unsigned int   u32;
typedef __bf16 bf16x8 __attribute__((ext_vector_type(8)));
typedef float  f32x4  __attribute__((ext_vector_type(4)));

// ---------- helpers ----------
__device__ __forceinline__ float bf2f(u16 v){ u32 u = ((u32)v) << 16; float f; __builtin_memcpy(&f,&u,4); return f; }
__device__ __forceinline__ u16 f2bf(float f){ u32 u; __builtin_memcpy(&u,&f,4); u32 r = (u + 0x7FFFu + ((u>>16)&1u)) >> 16; return (u16)r; }
__device__ __forceinline__ float silu(float v){ return v / (1.f + __expf(-v)); }

__device__ __forceinline__ void gload_lds16(const u16* g, u16* l){
  __builtin_amdgcn_global_load_lds((const __attribute__((address_space(1))) void*)g,
                                   (__attribute__((address_space(3))) void*)l, 16, 0, 0);
}

#define FENCE asm volatile("" ::: "memory")
#define BARRIER do{ FENCE; __builtin_amdgcn_s_barrier(); FENCE; }while(0)

// Geometry: B=16, C1=128, C2=256, H=W=128, padded spatial 130x130 (1-px zero halo)
#define HP 130
#define XPIX 128
#define YPIX 256
#define XIMG (HP*HP*XPIX)
#define YIMG (HP*HP*YPIX)

// ---------- small prep kernels ----------
__global__ void prep_coef(const float* __restrict__ gamma, const float* __restrict__ beta,
                          const float* __restrict__ mean,  const float* __restrict__ var,
                          const float* __restrict__ b1, float2* __restrict__ coefA, float2* __restrict__ coefB){
  int c = threadIdx.x;
  float s = gamma[c] * rsqrtf(var[c] + 1e-5f);
  float t = beta[c] - mean[c] * s;
  coefA[c] = make_float2(s, t);
  coefB[c] = make_float2(s, b1[c] * s + t);
}

// w3p[n][k] bf16, k = (kh*3+kw)*128 + c
__global__ void repack_w3(const float* __restrict__ w, u16* __restrict__ w3p){
  int idx = blockIdx.x*256 + threadIdx.x;
  int n = idx / 1152, k = idx % 1152;
  int tap = k >> 7, c = k & 127;
  int kh = tap / 3, kw = tap % 3;
  w3p[idx] = f2bf(w[((n*128 + c)*3 + kh)*3 + kw]);
}

__global__ void repack_w1(const float* __restrict__ w, u16* __restrict__ w1p){
  int idx = blockIdx.x*256 + threadIdx.x;
  w1p[idx] = f2bf(w[idx]);
}

__device__ __forceinline__ void halo_pix(int pi, int& hp, int& wp){
  if (pi < 130){ hp = 0; wp = pi; }
  else if (pi < 260){ hp = 129; wp = pi - 130; }
  else { int j = pi - 260; hp = 1 + (j >> 1); wp = (j & 1) ? 129 : 0; }
}
__global__ void zero_halos(u16* __restrict__ xpad, u16* __restrict__ ypad, int cimg){
  int idx = blockIdx.x*256 + threadIdx.x;
  const int NX = cimg*516*16;
  uint4 z = make_uint4(0u,0u,0u,0u);
  if (idx < NX){
    int b = idx / (516*16), rr = idx % (516*16);
    int pi = rr >> 4, cch = rr & 15, hp, wp;
    halo_pix(pi, hp, wp);
    *(uint4*)(xpad + (((size_t)b*HP + hp)*HP + wp)*XPIX + cch*8) = z;
  } else {
    idx -= NX;
    if (idx < cimg*516*32){
      int b = idx / (516*32), rr = idx % (516*32);
      int pi = rr >> 5, cch = rr & 31, hp, wp;
      halo_pix(pi, hp, wp);
      *(uint4*)(ypad + (((size_t)b*HP + hp)*HP + wp)*YPIX + cch*8) = z;
    }
  }
}

// fp32 NCHW -> padded bf16 NHWC transpose
__global__ __launch_bounds__(256) void transpose_x(const float* __restrict__ x, u16* __restrict__ xpad, int b0){
  __shared__ u16 s[64][66];
  const int tid = threadIdx.x, bid = blockIdx.x;
  const int ct = bid & 1, wt = (bid >> 1) & 1, row = bid >> 2;
  const int bl = row >> 7, h = row & 127;
  const int c0 = ct << 6, w0 = wt << 6;
  {
    const int lw = tid & 63, lc4 = tid >> 6;
    const size_t xb = ((size_t)(b0 + bl)*128)*16384 + (size_t)h*128 + w0 + lw;
    #pragma unroll
    for (int r = 0; r < 16; ++r){
      int c = r*4 + lc4;
      s[c][lw] = f2bf(x[xb + (size_t)(c0 + c)*16384]);
    }
  }
  __syncthreads();
  {
    const int lw = tid >> 5, lcp = (tid & 31) << 1;
    const size_t pb = ((size_t)bl*HP + h + 1)*HP;
    #pragma unroll
    for (int r = 0; r < 8; ++r){
      int w = r*8 + lw;
      u32 v = (u32)s[lcp][w] | ((u32)s[lcp+1][w] << 16);
      *(u32*)(xpad + (pb + (w0 + w + 1))*XPIX + c0 + lcp) = v;
    }
  }
}

// ---------- stage A: conv3x3 implicit GEMM, 256x256 tile, BK=64 ----------
// 2 phases per K-tile (P0: a0 + all B, 32 MFMA; P1: a1, 32 MFMA), 2 barriers/tile.
// Persistent wg: each processes BPW bands in a flat loop; staging pipelines through
// the band seam so the epilogue overlaps the next band's prologue loads.
// Reads always hit buf[pr]; stage writes always hit buf[pr^1] -> no pre-MFMA barrier.
// vmcnt: mid-tile (4) ensures own A.h1 landed; end-tile (2) ensures next tile's
// A.h0/B.h0/B.h1 landed (A.h1 stays in flight).

__device__ __forceinline__ int offA_of(int Ts){
  int tap = Ts >> 1;
  int kh = (tap*11) >> 5;            // tap/3 for tap<=9
  int kw = tap - kh*3;
  return kh*(HP*XPIX) + kw*XPIX + ((Ts & 1) << 6);
}

__global__ __launch_bounds__(512, 2) void convA(const u16* __restrict__ xpad, const u16* __restrict__ w3p,
                                                const float2* __restrict__ coefA, u16* __restrict__ ypad,
                                                int BPW){
  __shared__ u16 sA[2][16384];
  __shared__ u16 sB[2][16384];
  const int t = threadIdx.x;
  const int nwg = gridDim.x;
  const int w = (blockIdx.x & 7)*(nwg >> 3) + (blockIdx.x >> 3);   // XCD-contiguous (nwg%8==0)
  const int band0 = w * BPW;
  const int bl = band0 >> 6;                 // BPW | 64 -> bl uniform per wg
  int h0 = (band0 & 63) << 1;
  const int lane = t & 63, wave = t >> 6;
  const int wm = wave & 1, wn = wave >> 1;   // 2(M) x 4(N) waves
  const int quad = lane >> 4, l16 = lane & 15;
  const int lc = t & 7;
  const u16* ximg = xpad + (size_t)bl * XIMG;

  // staging descriptors: [half][q] -> global base (pre-swizzled), LDS elem offset
  const u16* gA[2][2]; int lA[2][2];
  const u16* gB[2][2]; int lB[2][2];
  #pragma unroll
  for (int ho = 0; ho < 2; ++ho)
    #pragma unroll
    for (int q = 0; q < 2; ++q){
      int r = ((t >> 6) << 4) + (q << 3) + ((t >> 3) & 7);
      int p = (ho << 6) + r + (r & 64);                  // ho=0: rows{0-63,128-191}
      gA[ho][q] = ximg + (size_t)((h0 + (p >> 7))*HP + (p & 127))*XPIX + ((lc ^ (p & 7)) << 3);
      lA[ho][q] = p*64 + lc*8;
      int n = ((r >> 5) << 6) + (ho << 5) + (r & 31);    // ho=0: n%64<32
      gB[ho][q] = w3p + (size_t)n*1152 + ((lc ^ (n & 7)) << 3);
      lB[ho][q] = n*64 + lc*8;
    }

  // fragment LDS offsets (elements), swizzled
  u32 fA[2][4][2], fB[4][2];
  #pragma unroll
  for (int hf = 0; hf < 2; ++hf)
    #pragma unroll
    for (int i = 0; i < 4; ++i)
      #pragma unroll
      for (int c = 0; c < 2; ++c){
        int row = wm*128 + hf*64 + i*16 + l16;
        fA[hf][i][c] = row*64 + (((c*4 + quad) ^ (row & 7)) << 3);
      }
  #pragma unroll
  for (int j = 0; j < 4; ++j)
    #pragma unroll
    for (int c = 0; c < 2; ++c){
      int row = wn*64 + j*16 + l16;
      fB[j][c] = row*64 + (((c*4 + quad) ^ (row & 7)) << 3);
    }

  f32x4 acc[8][4];
  #pragma unroll
  for (int i = 0; i < 8; ++i)
    #pragma unroll
    for (int j = 0; j < 4; ++j){ f32x4 z = {0.f,0.f,0.f,0.f}; acc[i][j] = z; }

  // prologue: stage tile 0 fully into buf0
  {
    gload_lds16(gA[0][0], sA[0] + lA[0][0]); gload_lds16(gA[0][1], sA[0] + lA[0][1]);
    gload_lds16(gB[0][0], sB[0] + lB[0][0]); gload_lds16(gB[0][1], sB[0] + lB[0][1]);
    gload_lds16(gB[1][0], sB[0] + lB[1][0]); gload_lds16(gB[1][1], sB[0] + lB[1][1]);
    gload_lds16(gA[1][0], sA[0] + lA[1][0]); gload_lds16(gA[1][1], sA[0] + lA[1][1]);
    asm volatile("s_waitcnt vmcnt(0)" ::: "memory");
  }
  BARRIER;

  const int UTOT = 18 * BPW;
  int tn = 0;
  for (int u = 0; u < UTOT; ++u){
    const int pr = u & 1;
    const u16* A = sA[pr]; const u16* B = sB[pr];
    u16* An = sA[pr ^ 1]; u16* Bn = sB[pr ^ 1];
    const bool last = (u == UTOT - 1);
    const int ntl = (tn == 17) ? 0 : tn + 1;
    if (tn == 17 && !last){                      // advance A descriptors to next band
      #pragma unroll
      for (int ho = 0; ho < 2; ++ho)
        #pragma unroll
        for (int q = 0; q < 2; ++q) gA[ho][q] += 2*HP*XPIX;
    }
    const int aoff = offA_of(ntl), boff = ntl*64;

    bf16x8 a[4][2], b[4][2];
    // ---- P0: read a0 + all B; stage (u+1).A.h0,B.h0; MFMA i=0..3 ----
    #pragma unroll
    for (int i = 0; i < 4; ++i){
      a[i][0] = *(const bf16x8*)(A + fA[0][i][0]);
      a[i][1] = *(const bf16x8*)(A + fA[0][i][1]);
    }
    #pragma unroll
    for (int j = 0; j < 4; ++j){
      b[j][0] = *(const bf16x8*)(B + fB[j][0]);
      b[j][1] = *(const bf16x8*)(B + fB[j][1]);
    }
    if (!last){
      gload_lds16(gA[0][0] + aoff, An + lA[0][0]); gload_lds16(gA[0][1] + aoff, An + lA[0][1]);
      gload_lds16(gB[0][0] + boff, Bn + lB[0][0]); gload_lds16(gB[0][1] + boff, Bn + lB[0][1]);
    }
    __builtin_amdgcn_s_setprio(1);
    #pragma unroll
    for (int i = 0; i < 4; ++i)
      #pragma unroll
      for (int j = 0; j < 4; ++j){
        acc[i][j] = __builtin_amdgcn_mfma_f32_16x16x32_bf16(a[i][0], b[j][0], acc[i][j], 0, 0, 0);
        acc[i][j] = __builtin_amdgcn_mfma_f32_16x16x32_bf16(a[i][1], b[j][1], acc[i][j], 0, 0, 0);
      }
    __builtin_amdgcn_s_setprio(0);
    if (last) asm volatile("s_waitcnt vmcnt(0)" ::: "memory");
    else      asm volatile("s_waitcnt vmcnt(4)" ::: "memory");
    BARRIER;

    // ---- P1: read a1; stage (u+1).B.h1,A.h1; MFMA i=4..7 ----
    #pragma unroll
    for (int i = 0; i < 4; ++i){
      a[i][0] = *(const bf16x8*)(A + fA[1][i][0]);
      a[i][1] = *(const bf16x8*)(A + fA[1][i][1]);
    }
    if (!last){
      gload_lds16(gB[1][0] + boff, Bn + lB[1][0]); gload_lds16(gB[1][1] + boff, Bn + lB[1][1]);
      gload_lds16(gA[1][0] + aoff, An + lA[1][0]); gload_lds16(gA[1][1] + aoff, An + lA[1][1]);
    }
    __builtin_amdgcn_s_setprio(1);
    #pragma unroll
    for (int i = 0; i < 4; ++i)
      #pragma unroll
      for (int j = 0; j < 4; ++j){
        acc[4+i][j] = __builtin_amdgcn_mfma_f32_16x16x32_bf16(a[i][0], b[j][0], acc[4+i][j], 0, 0, 0);
        acc[4+i][j] = __builtin_amdgcn_mfma_f32_16x16x32_bf16(a[i][1], b[j][1], acc[4+i][j], 0, 0, 0);
      }
    __builtin_amdgcn_s_setprio(0);
    if (!last) asm volatile("s_waitcnt vmcnt(2)" ::: "memory");
    BARRIER;

    if (tn == 17){
      // epilogue: BN + SiLU -> ypad ; overlaps next band's staged loads in flight
      float2 co[4];
      #pragma unroll
      for (int j = 0; j < 4; ++j) co[j] = coefA[wn*64 + j*16 + l16];
      #pragma unroll
      for (int ig = 0; ig < 8; ++ig){
        const int pb = wm*128 + ig*16 + quad*4;
        #pragma unroll
        for (int r = 0; r < 4; ++r){
          const int p = pb + r;
          const int hh = h0 + (p >> 7), ww = p & 127;
          u16* dst = ypad + ((size_t)(bl*HP + hh + 1)*HP + (ww + 1))*YPIX + wn*64;
          #pragma unroll
          for (int j = 0; j < 4; ++j){
            float v = acc[ig][j][r]*co[j].x + co[j].y;
            dst[j*16 + l16] = f2bf(silu(v));
          }
        }
      }
      asm volatile("s_waitcnt vmcnt(0)" ::: "memory");   // drain stores so counted vmcnt stays valid
      h0 += 2;
      tn = 0;
      #pragma unroll
      for (int i = 0; i < 8; ++i)
        #pragma unroll
        for (int j = 0; j < 4; ++j){ f32x4 z = {0.f,0.f,0.f,0.f}; acc[i][j] = z; }
    } else ++tn;
  }
}

// ---------- stage B: shift + conv1x1 + bias + BN + residual + SiLU -> out (NCHW fp32) ----------
// [128px][64ch] LDS tiles, XOR-swizzled (conflict-free), 4 K-steps of 32 MFMA,
// double-buffered with stage-ahead; 64 KiB LDS -> 2 blocks/CU.
__global__ __launch_bounds__(256, 2) void convB(const u16* __restrict__ ypad, const u16* __restrict__ w1p,
                                                const float2* __restrict__ coefB, float* __restrict__ out, int b0){
  __shared__ u16 sAct[2][8192];
  __shared__ u16 sW[2][8192];
  const int tid = threadIdx.x;
  const int nwg = gridDim.x;
  const int bidl = (blockIdx.x & 7)*(nwg >> 3) + (blockIdx.x >> 3);  // XCD swizzle
  const int nt = bidl & 1, row = bidl >> 1;
  const int bl = row >> 7, h = row & 127;
  const int n0 = nt << 7;
  const int lane = tid & 63, wave = tid >> 6;
  const int wc = wave & 1, wpx = wave >> 1;
  const int quad = lane >> 4, l16 = lane & 15;

  const size_t imgy = (size_t)bl * YIMG;

  // staging descriptors: 4 act + 4 wts chunk-loads per thread per K-step
  const u16* gact[4]; const u16* gwt[4]; int ldst[4];
  #pragma unroll
  for (int l = 0; l < 4; ++l){
    int id = l*256 + tid;            // 0..1023
    int p = id >> 3, c = id & 7;
    gact[l] = ypad + imgy + (size_t)(h*HP)*YPIX + (size_t)p*YPIX + ((c ^ (p & 7)) << 3);
    gwt[l]  = w1p + (size_t)(n0 + p)*256 + ((c ^ (p & 7)) << 3);
    ldst[l] = id*8;
  }

  // fragment offsets
  u32 fW[4][2], fAc[4][2];
  #pragma unroll
  for (int i = 0; i < 4; ++i)
    #pragma unroll
    for (int k = 0; k < 2; ++k){
      int rn = wc*64 + i*16 + l16;
      fW[i][k] = rn*64 + (((k*4 + quad) ^ (rn & 7)) << 3);
      int rp = wpx*64 + i*16 + l16;
      fAc[i][k] = rp*64 + (((k*4 + quad) ^ (rp & 7)) << 3);
    }

  f32x4 acc[4][4];
  #pragma unroll
  for (int i = 0; i < 4; ++i)
    #pragma unroll
    for (int j = 0; j < 4; ++j){ f32x4 zz = {0.f,0.f,0.f,0.f}; acc[i][j] = zz; }

  // prologue: stage g=0 (shift g0: pad(h+1, w+0))
  {
    const int aoff = (1*HP + 0)*YPIX + 0;
    #pragma unroll
    for (int l = 0; l < 4; ++l){
      gload_lds16(gact[l] + aoff, sAct[0] + ldst[l]);
      gload_lds16(gwt[l],         sW[0]   + ldst[l]);
    }
    asm volatile("s_waitcnt vmcnt(0)" ::: "memory");
  }
  BARRIER;

  #pragma unroll
  for (int g = 0; g < 4; ++g){
    const int pr = g & 1;
    if (g < 3){
      const int gg = g + 1;
      const int dhp = (gg == 1) ? 2 : ((gg == 3) ? 0 : 1);
      const int dwp = (gg == 0) ? 0 : ((gg == 2) ? 2 : 1);
      const int aoff = (dhp*HP + dwp)*YPIX + gg*64;
      const int woff = gg*64;
      #pragma unroll
      for (int l = 0; l < 4; ++l){
        gload_lds16(gact[l] + aoff, sAct[pr^1] + ldst[l]);
        gload_lds16(gwt[l] + woff,  sW[pr^1]   + ldst[l]);
      }
    }
    bf16x8 wf[4][2], af[4][2];
    #pragma unroll
    for (int i = 0; i < 4; ++i){
      wf[i][0] = *(const bf16x8*)(sW[pr] + fW[i][0]);
      wf[i][1] = *(const bf16x8*)(sW[pr] + fW[i][1]);
      af[i][0] = *(const bf16x8*)(sAct[pr] + fAc[i][0]);
      af[i][1] = *(const bf16x8*)(sAct[pr] + fAc[i][1]);
    }
    __builtin_amdgcn_s_setprio(1);
    #pragma unroll
    for (int i = 0; i < 4; ++i)
      #pragma unroll
      for (int j = 0; j < 4; ++j){
        acc[i][j] = __builtin_amdgcn_mfma_f32_16x16x32_bf16(wf[i][0], af[j][0], acc[i][j], 0, 0, 0);
        acc[i][j] = __builtin_amdgcn_mfma_f32_16x16x32_bf16(wf[i][1], af[j][1], acc[i][j], 0, 0, 0);
      }
    __builtin_amdgcn_s_setprio(0);
    asm volatile("s_waitcnt vmcnt(0)" ::: "memory");
    BARRIER;
  }

  // D[channel = n0+wc*64+i*16+quad*4+r][pixel = wpx*64+j*16+l16]
  const size_t ybase = ((size_t)(bl*HP + h + 1))*HP*YPIX;
  const size_t obase = (size_t)(b0 + bl)*256*16384 + (size_t)h*128;
  #pragma unroll
  for (int i = 0; i < 4; ++i){
    const int chb = n0 + wc*64 + i*16 + quad*4;
    const float2 c0 = coefB[chb+0], c1 = coefB[chb+1], c2 = coefB[chb+2], c3 = coefB[chb+3];
    float* ob = out + obase + (size_t)chb*16384;
    #pragma unroll
    for (int j = 0; j < 4; ++j){
      const int p = wpx*64 + j*16 + l16;
      const ushort4 rv = *(const ushort4*)&ypad[ybase + (size_t)(p + 1)*YPIX + chb];  // residual
      ob[p]             = silu(acc[i][j][0]*c0.x + c0.y + bf2f(rv.x));
      ob[16384 + p]     = silu(acc[i][j][1]*c1.x + c1.y + bf2f(rv.y));
      ob[2*16384 + p]   = silu(acc[i][j][2]*c2.x + c2.y + bf2f(rv.z));
      ob[3*16384 + p]   = silu(acc[i][j][3]*c3.x + c3.y + bf2f(rv.w));
    }
  }
}

// ---------- launch ----------
extern "C" void kernel_launch(void* const* d_in, const int* in_sizes, int n_in,
                              void* d_out, int out_size, void* d_ws, size_t ws_size,
                              hipStream_t stream){
  const float* x  = (const float*)d_in[0];
  const float* w3 = (const float*)d_in[1];
  const float* w1 = (const float*)d_in[2];
  const float* b1 = (const float*)d_in[3];
  const float* gm = (const float*)d_in[4];
  const float* bt = (const float*)d_in[5];
  const float* mn = (const float*)d_in[6];
  const float* vr = (const float*)d_in[7];
  float* outp = (float*)d_out;

  char* ws = (char*)d_ws;
  float2* coefA = (float2*)ws;
  float2* coefB = coefA + 256;
  u16*    w3p   = (u16*)(ws + 4096);
  u16*    w1p   = (u16*)(ws + 4096 + 589824);
  const size_t fixed = 4096 + 589824 + 131072;
  int cimg = 16;
  while (cimg > 1 && fixed + (size_t)cimg*12979200ull > ws_size) cimg >>= 1;
  u16* xpad = (u16*)(ws + fixed);
  u16* ypad = (u16*)(ws + fixed + (size_t)cimg*4326400ull);

  prep_coef<<<1, 256, 0, stream>>>(gm, bt, mn, vr, b1, coefA, coefB);
  repack_w3<<<1152, 256, 0, stream>>>(w3, w3p);
  repack_w1<<<256, 256, 0, stream>>>(w1, w1p);
  {
    int nthr = cimg*516*48;
    zero_halos<<<(nthr + 255)/256, 256, 0, stream>>>(xpad, ypad, cimg);
  }
  const int bands = 64*cimg;
  const int BPW = (bands >= 1024) ? 4 : (bands >= 512 ? 2 : 1);   // BPW | 64
  const int nwgA = bands / BPW;                                    // %8 == 0
  for (int b0 = 0; b0 < 16; b0 += cimg){
    transpose_x<<<4*128*cimg, 256, 0, stream>>>(x, xpad, b0);
    convA<<<nwgA, 512, 0, stream>>>(xpad, w3p, coefA, ypad, BPW);
    convB<<<2*128*cimg, 256, 0, stream>>>(ypad, w1p, coefB, outp, b0);
  }
}